// Round 5
// baseline (212.441 us; speedup 1.0000x reference)
//
#include <hip/hip_runtime.h>

typedef __attribute__((ext_vector_type(8))) short short8;
typedef __attribute__((ext_vector_type(4))) short short4v;
typedef __attribute__((ext_vector_type(4))) float floatx4;
typedef __attribute__((ext_vector_type(16))) float floatx16;
typedef __attribute__((ext_vector_type(2))) int iv2;

#define GLOBAL_AS __attribute__((address_space(1)))
#define LDS_AS __attribute__((address_space(3)))

__device__ __forceinline__ short f2bs(float f) {
    // RNE float -> bf16 (as short). Inputs finite here.
    union { float f; unsigned u; } v; v.f = f;
    unsigned r = v.u + 0x7fffu + ((v.u >> 16) & 1u);
    return (short)(r >> 16);
}

#if __has_builtin(__builtin_amdgcn_cvt_pk_bf16_f32)
typedef __attribute__((ext_vector_type(2))) __bf16 bf16x2;
__device__ __forceinline__ unsigned pk2(float a, float b) {
    union { bf16x2 v; unsigned u; } u;
    u.v = __builtin_amdgcn_cvt_pk_bf16_f32(a, b);
    return u.u;
}
#else
__device__ __forceinline__ unsigned pk2(float a, float b) {
    // round-half-up, non-negative finite inputs
    union { float f; unsigned u; } x, y; x.f = a; y.f = b;
    return ((y.u + 0x8000u) & 0xffff0000u) | ((x.u + 0x8000u) >> 16);
}
#endif

// ---------------- fused cast fp32 -> bf16 (x + Wq + Wk + Wv) ----------------
__global__ __launch_bounds__(256) void cast_all(const float* __restrict__ x,
                                                const float* __restrict__ Wq,
                                                const float* __restrict__ Wk,
                                                const float* __restrict__ Wv,
                                                short* __restrict__ xb,
                                                short* __restrict__ wb) {
    int b = blockIdx.x;
    int t = threadIdx.x;
    const float* src;
    short* dst;
    int idx;
    if (b < 8192) {
        src = x; dst = xb; idx = b * 1024 + t * 4;
    } else {
        int r = b - 8192;
        int wz = r >> 10;
        src = (wz == 0) ? Wq : (wz == 1) ? Wk : Wv;
        dst = wb + wz * (1 << 20);
        idx = (r & 1023) * 1024 + t * 4;
    }
    float4 v = *(const float4*)(src + idx);
    short4v o;
    o.x = f2bs(v.x); o.y = f2bs(v.y); o.z = f2bs(v.z); o.w = f2bs(v.w);
    *(short4v*)(dst + idx) = o;
}

// ---------------- QKV GEMM v4: 256x256 tile, 8 waves (2Mx4N, wave tile 128x64), R4 schedule ----------------
// EXACT R4 dbuf/vmcnt schedule scaled up: per K-step {bar(WAR) -> STAGE(buf^1,T+1)=8 loads ->
// vmcnt(8) -> bar(RAW) -> 24 ds_read_b128 + 64 MFMA}. One flat compute body, compiler-scheduled.
// Rationale (R4 counters): 128^2 is LDS-pipe-bound (192KB LDS traffic per 4.2 MFLOP, MfmaUtil
// ceiling ~46%). 128x64 wave tiles halve read amplification per FLOP: 256KB per 8.4 MFLOP ->
// ceiling ~68%. LDS 128KB dbuf -> 1 block/CU, 2 waves/SIMD (same waves/SIMD as R4).
__global__ __launch_bounds__(512, 2) void qkv_gemm(const short* __restrict__ xb,
                                                   const short* __restrict__ wb,
                                                   short* __restrict__ qout,
                                                   short* __restrict__ kout,
                                                   short* __restrict__ vtout) {
    __shared__ short As[2][256 * 64];  // [m][k], 16B chunks XOR-swizzled: slot = chunk ^ (row&7)
    __shared__ short Bs[2][256 * 64];
    const int K = 1024;
    int tid = threadIdx.x;   // 0..511
    int lane = tid & 63;
    int wid = tid >> 6;      // 0..7
    int quad = lane >> 4;
    int l16 = lane & 15;
    int wm = (wid >> 2) * 128;  // 2 M-groups: wave rows 128
    int wn = (wid & 3) * 64;    // 4 N-groups: wave cols 64
    int bm = blockIdx.x * 256;
    int bn = blockIdx.y * 256;
    const short* W = wb + (size_t)blockIdx.z * K * 1024;

    floatx4 acc[8][4];
#pragma unroll
    for (int i = 0; i < 8; i++)
#pragma unroll
        for (int j = 0; j < 4; j++) acc[i][j] = (floatx4){0.f, 0.f, 0.f, 0.f};

    int srow = tid >> 3;                     // 0..63
    int ssw = ((tid & 7) ^ (srow & 7)) * 8;  // source-side swizzle (LDS dest linear)

    // Per STAGE: 4 A-ops + 4 B-ops, each op = 512 thr x 16B = 64 rows x 64k. 8 loads/thread.
#define STAGE_AB(cb, kk) do { \
    _Pragma("unroll") for (int l = 0; l < 4; l++) { \
        const short* g = xb + (size_t)(bm + srow + l * 64) * K + (kk) + ssw; \
        __builtin_amdgcn_global_load_lds((const GLOBAL_AS void*)g, \
            (LDS_AS void*)(&As[cb][0] + tid * 8 + l * 4096), 16, 0, 0); \
    } \
    _Pragma("unroll") for (int l = 0; l < 4; l++) { \
        const short* g = W + (size_t)(bn + srow + l * 64) * K + (kk) + ssw; \
        __builtin_amdgcn_global_load_lds((const GLOBAL_AS void*)g, \
            (LDS_AS void*)(&Bs[cb][0] + tid * 8 + l * 4096), 16, 0, 0); \
    } \
} while (0)

    STAGE_AB(0, 0);

    for (int T = 0; T < 16; T++) {
        int cur = T & 1;
        // WAR guard: all waves done reading buf[cur^1] (step T-1)
        __builtin_amdgcn_sched_barrier(0);
        __builtin_amdgcn_s_barrier();
        __builtin_amdgcn_sched_barrier(0);
        if (T < 15) {
            STAGE_AB(cur ^ 1, (T + 1) * 64);
            asm volatile("s_waitcnt vmcnt(8)" ::: "memory");  // step-T loads (mine) done
        } else {
            asm volatile("s_waitcnt vmcnt(0)" ::: "memory");
        }
        __builtin_amdgcn_sched_barrier(0);
        __builtin_amdgcn_s_barrier();   // step-T LDS visible to all waves
        __builtin_amdgcn_sched_barrier(0);

        const short* Ac = &As[cur][0];
        const short* Bc = &Bs[cur][0];
#pragma unroll
        for (int s = 0; s < 2; s++) {
            int slot = ((s * 4 + quad) ^ (l16 & 7)) * 8;
            short8 af[8], bf[4];
#pragma unroll
            for (int i = 0; i < 8; i++)
                af[i] = *(const short8*)(Ac + (wm + i * 16 + l16) * 64 + slot);
#pragma unroll
            for (int j = 0; j < 4; j++)
                bf[j] = *(const short8*)(Bc + (wn + j * 16 + l16) * 64 + slot);
#pragma unroll
            for (int i = 0; i < 8; i++)
#pragma unroll
                for (int j = 0; j < 4; j++)
                    acc[i][j] = __builtin_amdgcn_mfma_f32_16x16x32_bf16(af[i], bf[j], acc[i][j], 0, 0, 0);
        }
    }
#undef STAGE_AB

    if (blockIdx.z == 2) {
#pragma unroll
        for (int i = 0; i < 8; i++) {
#pragma unroll
            for (int j = 0; j < 4; j++) {
                int m = bm + wm + i * 16 + quad * 4;
                int c = bn + wn + j * 16 + l16;
                int b = m >> 11, nn = m & 2047, h = c >> 6, dd = c & 63;
                short4v pk;
                pk.x = f2bs(acc[i][j][0]);
                pk.y = f2bs(acc[i][j][1]);
                pk.z = f2bs(acc[i][j][2]);
                pk.w = f2bs(acc[i][j][3]);
                *(short4v*)(vtout + ((size_t)(b * 16 + h) * 64 + dd) * 2048 + nn) = pk;
            }
        }
    } else {
        short* dst = (blockIdx.z == 0) ? qout : kout;
        float qs = (blockIdx.z == 0) ? 0.180336881f : 1.0f;  // 0.125*log2(e) folded into Q
#pragma unroll
        for (int i = 0; i < 8; i++) {
#pragma unroll
            for (int j = 0; j < 4; j++) {
#pragma unroll
                for (int r = 0; r < 4; r++) {
                    int m = bm + wm + i * 16 + quad * 4 + r;
                    int c = bn + wn + j * 16 + l16;
                    dst[((size_t)((m >> 11) * 16 + (c >> 6)) * 2048 + (m & 2047)) * 64 + (c & 63)] =
                        f2bs(acc[i][j][r] * qs);
                }
            }
        }
    }
}

// ---------------- Flash attention v2b: in-register P (permlane32_swap) + K/V dbuf ----------------
// q: pre-scaled bf16 [b,h,2048,64]; k: [b,h,2048,64]; vt: [b,h,64,2048]; out fp32 [b,2048,1024]
// S^T = K*Q^T: lane owns ONE q-column. P never touches LDS.
// Exchange derivation (C/D map row=(e&3)+8(e>>2)+4*half): for K-step s (sb=s&1), consumer half h
// needs keys 16sb+8h+{0..7}, ALL from quad g=2sb+h: j0..3 from half-0 owner, j4..7 from half-1 owner.
// permlane32_swap(a=W[2sb], b=W[2sb+1]) -> r.x = {a_low, b_low} = j01/j23 dword for both halves,
// r.y = {a_high, b_high} = j45/j67 dword for both halves.
__global__ __launch_bounds__(256, 2) void attn(const short* __restrict__ q,
                                               const short* __restrict__ k,
                                               const short* __restrict__ vt,
                                               float* __restrict__ out) {
    __shared__ short Ks[2][128 * 64];   // [key][d], 16B slot = chunk ^ (key&7)
    __shared__ short Vs[2][64 * 128];   // [d][key], 16B slot = (c&8)|((c^(d&7))&7)

    int tid = threadIdx.x;
    int lane = tid & 63;
    int wid = tid >> 6;
    int l32 = lane & 31;
    int half = lane >> 5;   // 0/1

    int flat = blockIdx.x;
    int xcd = flat & 7;
    int slot = flat >> 3;            // 0..63
    int bh = xcd * 8 + (slot >> 3);  // 8 (b,h) per XCD
    int qx = slot & 7;
    int b = bh >> 4, h = bh & 15;

    const short* qp = q + (size_t)(b * 16 + h) * 2048 * 64;
    const short* kp = k + (size_t)(b * 16 + h) * 2048 * 64;
    const short* vp = vt + (size_t)(b * 16 + h) * 64 * 2048;

    // K staging: 128x64. row = (tid>>3)+l*32, chunk = tid&7 (swizzled at source)
    int krow = tid >> 3;
    int ksw = ((tid & 7) ^ (krow & 7)) * 8;
    // V staging: 64x128. d = (tid>>4)+l*16, chunk16 = tid&15
    int vd = tid >> 4;
    int vc = tid & 15;
    int vsw = ((vc & 8) | ((vc ^ vd) & 7)) * 8;

#define STAGE_KV(cb, kvb) do { \
    _Pragma("unroll") for (int l = 0; l < 4; l++) { \
        const short* g = kp + (size_t)((kvb) + krow + l * 32) * 64 + ksw; \
        __builtin_amdgcn_global_load_lds((const GLOBAL_AS void*)g, \
            (LDS_AS void*)(&Ks[cb][0] + tid * 8 + l * 2048), 16, 0, 0); \
    } \
    _Pragma("unroll") for (int l = 0; l < 4; l++) { \
        const short* g = vp + (size_t)(vd + l * 16) * 2048 + (kvb) + vsw; \
        __builtin_amdgcn_global_load_lds((const GLOBAL_AS void*)g, \
            (LDS_AS void*)(&Vs[cb][0] + tid * 8 + l * 2048), 16, 0, 0); \
    } \
} while (0)

    for (int phase = 0; phase < 2; phase++) {
        int qt = (phase == 0) ? qx : (15 - qx);
        int qbase = qt * 128;
        int qrow_w = qbase + wid * 32;      // wave owns q-rows qrow_w .. qrow_w+31
        int qlane = qrow_w + l32;           // this lane's q-row (S^T col)

        // Q fragments as B-operand: n = l32 (q-row), k = half*8 + j, 4 K-steps over d=64
        short8 qf[4];
#pragma unroll
        for (int s = 0; s < 4; s++)
            qf[s] = *(const short8*)(qp + (size_t)qlane * 64 + s * 16 + half * 8);

        floatx16 oacc[2];
#pragma unroll
        for (int nt = 0; nt < 2; nt++)
#pragma unroll
            for (int e = 0; e < 16; e++) oacc[nt][e] = 0.f;
        float rs = 0.f;

        int ntiles = qt + 1;

        // phase prologue: guard vs previous phase's reads of buf0, then stage tile 0
        __builtin_amdgcn_sched_barrier(0);
        __builtin_amdgcn_s_barrier();
        __builtin_amdgcn_sched_barrier(0);
        STAGE_KV(0, 0);

        for (int t = 0; t < ntiles; t++) {
            int cur = t & 1;
            int kvb = t * 128;

            // write-after-read guard: all waves done reading buf[cur^1] (tile t-1)
            __builtin_amdgcn_sched_barrier(0);
            __builtin_amdgcn_s_barrier();
            __builtin_amdgcn_sched_barrier(0);
            if (t + 1 < ntiles) {
                STAGE_KV(cur ^ 1, kvb + 128);
                asm volatile("s_waitcnt vmcnt(8)" ::: "memory");  // tile-t loads (mine) done
            } else {
                asm volatile("s_waitcnt vmcnt(0)" ::: "memory");
            }
            __builtin_amdgcn_sched_barrier(0);
            __builtin_amdgcn_s_barrier();   // tile-t LDS visible to all waves
            __builtin_amdgcn_sched_barrier(0);

            const short* Kc = &Ks[cur][0];
            const short* Vc = &Vs[cur][0];

            // ---- S^T[key 0..127][q 0..31] = K * Q^T ----
            floatx16 sacc[4];
#pragma unroll
            for (int kb = 0; kb < 4; kb++)
#pragma unroll
                for (int e = 0; e < 16; e++) sacc[kb][e] = 0.f;
#pragma unroll
            for (int s = 0; s < 4; s++) {   // d-dim K-steps
#pragma unroll
                for (int kb = 0; kb < 4; kb++) {
                    int key = kb * 32 + l32;
                    int c = s * 2 + half;
                    short8 kf = *(const short8*)(Kc + key * 64 + ((c ^ (key & 7)) * 8));
                    sacc[kb] = __builtin_amdgcn_mfma_f32_32x32x16_bf16(kf, qf[s], sacc[kb], 0, 0, 0);
                }
            }

            // ---- exp2 + mask (diag tile only) + local row-sum + in-register pack ----
            // quad g of block kb holds keys kb*32 + 8g + 4*half + {0..3} for q=l32:
            //   W0 = pk2(keys+0,+1), W1 = pk2(keys+2,+3)
            bool diag = (t == ntiles - 1) && (kvb + 127 > qrow_w);
            unsigned W0[4][4], W1[4][4];
#pragma unroll
            for (int kb = 0; kb < 4; kb++) {
#pragma unroll
                for (int e = 0; e < 16; e++) {
                    float p = __builtin_amdgcn_exp2f(sacc[kb][e]);
                    if (diag) {
                        int key = kvb + kb * 32 + (e & 3) + 8 * (e >> 2) + 4 * half;
                        p = (key > qlane) ? 0.f : p;
                    }
                    sacc[kb][e] = p;
                    rs += p;
                }
#pragma unroll
                for (int g = 0; g < 4; g++) {
                    W0[kb][g] = pk2(sacc[kb][4 * g + 0], sacc[kb][4 * g + 1]);
                    W1[kb][g] = pk2(sacc[kb][4 * g + 2], sacc[kb][4 * g + 3]);
                }
            }

            // ---- O += P * V : A-frag P[q=l32][keys 16s + 8*half + 0..7] via permlane32_swap ----
            // r0 = swap(W0[2sb], W0[2sb+1]): r0.x -> dword0 (keys +0,+1), r0.y -> dword2 (+4,+5)
            // r1 = swap(W1[2sb], W1[2sb+1]): r1.x -> dword1 (+2,+3),      r1.y -> dword3 (+6,+7)
#pragma unroll
            for (int s = 0; s < 8; s++) {   // key K-steps of 16
                int kb = s >> 1;
                int g0 = (s & 1) * 2;       // quad for half-0 consumers
                int g1 = g0 + 1;            // quad for half-1 consumers
                iv2 r0 = __builtin_amdgcn_permlane32_swap(W0[kb][g0], W0[kb][g1], false, false);
                iv2 r1 = __builtin_amdgcn_permlane32_swap(W1[kb][g0], W1[kb][g1], false, false);
                union { int4 v; short8 s8; } pu;
                pu.v.x = r0.x; pu.v.y = r1.x; pu.v.z = r0.y; pu.v.w = r1.y;
                short8 pf = pu.s8;
#pragma unroll
                for (int nt = 0; nt < 2; nt++) {
                    int d = nt * 32 + l32;
                    int c = s * 2 + half;
                    int sl = (c & 8) | ((c ^ (d & 7)) & 7);
                    short8 vf = *(const short8*)(Vc + d * 128 + sl * 8);
                    oacc[nt] = __builtin_amdgcn_mfma_f32_32x32x16_bf16(pf, vf, oacc[nt], 0, 0, 0);
                }
            }
        }

        // ---- epilogue: rows of O live across lanes; fetch 1/l via shuffle ----
        float tot = rs + __shfl_xor(rs, 32);
        float inv = 1.0f / tot;
        float invr[16];
#pragma unroll
        for (int e = 0; e < 16; e++)
            invr[e] = __shfl(inv, (e & 3) + 8 * (e >> 2) + 4 * half);
#pragma unroll
        for (int nt = 0; nt < 2; nt++) {
#pragma unroll
            for (int e = 0; e < 16; e++) {
                int r = (e & 3) + 8 * (e >> 2) + 4 * half;
                int nn = qrow_w + r;
                out[((size_t)b * 2048 + nn) * 1024 + h * 64 + nt * 32 + l32] = oacc[nt][e] * invr[e];
            }
        }
    }
#undef STAGE_KV
}

extern "C" void kernel_launch(void* const* d_in, const int* in_sizes, int n_in,
                              void* d_out, int out_size, void* d_ws, size_t ws_size,
                              hipStream_t stream) {
    const float* x = (const float*)d_in[0];
    const float* Wq = (const float*)d_in[1];
    const float* Wk = (const float*)d_in[2];
    const float* Wv = (const float*)d_in[3];
    float* out = (float*)d_out;
    char* ws = (char*)d_ws;

    short* xb = (short*)ws;                          // 16 MB: [8192,1024] bf16
    short* wb = (short*)(ws + (16u << 20));          //  6 MB: [3,1024,1024] bf16
    short* qb = (short*)(ws + (22u << 20));          // 16 MB: [4,16,2048,64]
    short* kb = (short*)(ws + (38u << 20));          // 16 MB: [4,16,2048,64]
    short* vtb = (short*)(ws + (54u << 20));         // 16 MB: [4,16,64,2048]

    cast_all<<<8192 + 3 * 1024, 256, 0, stream>>>(x, Wq, Wk, Wv, xb, wb);
    qkv_gemm<<<dim3(32, 4, 3), 512, 0, stream>>>(xb, wb, qb, kb, vtb);
    attn<<<512, 256, 0, stream>>>(qb, kb, vtb, out);
}

// Round 6
// 198.223 us; speedup vs baseline: 1.0717x; 1.0717x over previous
//
#include <hip/hip_runtime.h>

typedef __attribute__((ext_vector_type(8))) short short8;
typedef __attribute__((ext_vector_type(4))) short short4v;
typedef __attribute__((ext_vector_type(4))) float floatx4;
typedef __attribute__((ext_vector_type(16))) float floatx16;
typedef __attribute__((ext_vector_type(2))) int iv2;

#define GLOBAL_AS __attribute__((address_space(1)))
#define LDS_AS __attribute__((address_space(3)))

__device__ __forceinline__ short f2bs(float f) {
    // RNE float -> bf16 (as short). Inputs finite here.
    union { float f; unsigned u; } v; v.f = f;
    unsigned r = v.u + 0x7fffu + ((v.u >> 16) & 1u);
    return (short)(r >> 16);
}

#if __has_builtin(__builtin_amdgcn_cvt_pk_bf16_f32)
typedef __attribute__((ext_vector_type(2))) __bf16 bf16x2;
__device__ __forceinline__ unsigned pk2(float a, float b) {
    union { bf16x2 v; unsigned u; } u;
    u.v = __builtin_amdgcn_cvt_pk_bf16_f32(a, b);
    return u.u;
}
#else
__device__ __forceinline__ unsigned pk2(float a, float b) {
    // round-half-up, non-negative finite inputs
    union { float f; unsigned u; } x, y; x.f = a; y.f = b;
    return ((y.u + 0x8000u) & 0xffff0000u) | ((x.u + 0x8000u) >> 16);
}
#endif

// ---------------- fused cast fp32 -> bf16 (x + Wq + Wk + Wv) ----------------
__global__ __launch_bounds__(256) void cast_all(const float* __restrict__ x,
                                                const float* __restrict__ Wq,
                                                const float* __restrict__ Wk,
                                                const float* __restrict__ Wv,
                                                short* __restrict__ xb,
                                                short* __restrict__ wb) {
    int b = blockIdx.x;
    int t = threadIdx.x;
    const float* src;
    short* dst;
    int idx;
    if (b < 8192) {
        src = x; dst = xb; idx = b * 1024 + t * 4;
    } else {
        int r = b - 8192;
        int wz = r >> 10;
        src = (wz == 0) ? Wq : (wz == 1) ? Wk : Wv;
        dst = wb + wz * (1 << 20);
        idx = (r & 1023) * 1024 + t * 4;
    }
    float4 v = *(const float4*)(src + idx);
    short4v o;
    o.x = f2bs(v.x); o.y = f2bs(v.y); o.z = f2bs(v.z); o.w = f2bs(v.w);
    *(short4v*)(dst + idx) = o;
}

// ---------------- QKV GEMM v3b: R4-proven 128x128 dbuf + XCD panel-grouping swizzle ----------------
// R4 schedule verbatim. New: m_tile = (bx>>3) + 8*(bx&7). Linear block id = bx + 64*(y+8z), so
// XCD = bx&7; all 8 y-blocks sharing an xb M-panel now sit on ONE XCD -> panel fetched from HBM
// once instead of up to 8x (R4 FETCH_SIZE 49 MB vs ~22 MB ideal).
__global__ __launch_bounds__(256) void qkv_gemm(const short* __restrict__ xb,
                                                const short* __restrict__ wb,
                                                short* __restrict__ qout,
                                                short* __restrict__ kout,
                                                short* __restrict__ vtout) {
    __shared__ short As[2][128 * 64];  // [m][k], 16B chunks XOR-swizzled: slot = chunk ^ (row&7)
    __shared__ short Bs[2][128 * 64];
    const int K = 1024;
    int tid = threadIdx.x;
    int lane = tid & 63;
    int wid = tid >> 6;
    int quad = lane >> 4;
    int l16 = lane & 15;
    int wm = (wid >> 1) * 64;
    int wn = (wid & 1) * 64;
    int bx = blockIdx.x;
    int bm = ((bx >> 3) + ((bx & 7) << 3)) * 128;   // XCD panel grouping (bijective on [0,64))
    int bn = blockIdx.y * 128;
    const short* W = wb + (size_t)blockIdx.z * K * 1024;

    floatx4 acc[4][4];
#pragma unroll
    for (int i = 0; i < 4; i++)
#pragma unroll
        for (int j = 0; j < 4; j++) acc[i][j] = (floatx4){0.f, 0.f, 0.f, 0.f};

    int srow = tid >> 3;
    int ssw = ((tid & 7) ^ (srow & 7)) * 8;

#define STAGE_AB(cb, kk) do { \
    _Pragma("unroll") for (int l = 0; l < 4; l++) { \
        const short* g = xb + (size_t)(bm + srow + l * 32) * K + (kk) + ssw; \
        __builtin_amdgcn_global_load_lds((const GLOBAL_AS void*)g, \
            (LDS_AS void*)(&As[cb][0] + tid * 8 + l * 2048), 16, 0, 0); \
    } \
    _Pragma("unroll") for (int l = 0; l < 4; l++) { \
        const short* g = W + (size_t)(bn + srow + l * 32) * K + (kk) + ssw; \
        __builtin_amdgcn_global_load_lds((const GLOBAL_AS void*)g, \
            (LDS_AS void*)(&Bs[cb][0] + tid * 8 + l * 2048), 16, 0, 0); \
    } \
} while (0)

    STAGE_AB(0, 0);

    for (int T = 0; T < 16; T++) {
        int cur = T & 1;
        // WAR guard: all waves done reading buf[cur^1] (step T-1)
        __builtin_amdgcn_sched_barrier(0);
        __builtin_amdgcn_s_barrier();
        __builtin_amdgcn_sched_barrier(0);
        if (T < 15) {
            STAGE_AB(cur ^ 1, (T + 1) * 64);
            asm volatile("s_waitcnt vmcnt(8)" ::: "memory");  // step-T loads (mine) done
        } else {
            asm volatile("s_waitcnt vmcnt(0)" ::: "memory");
        }
        __builtin_amdgcn_sched_barrier(0);
        __builtin_amdgcn_s_barrier();   // step-T LDS visible to all waves
        __builtin_amdgcn_sched_barrier(0);

        const short* Ac = &As[cur][0];
        const short* Bc = &Bs[cur][0];
#pragma unroll
        for (int s = 0; s < 2; s++) {
            int slot = ((s * 4 + quad) ^ (l16 & 7)) * 8;
            short8 af[4], bf[4];
#pragma unroll
            for (int i = 0; i < 4; i++)
                af[i] = *(const short8*)(Ac + (wm + i * 16 + l16) * 64 + slot);
#pragma unroll
            for (int j = 0; j < 4; j++)
                bf[j] = *(const short8*)(Bc + (wn + j * 16 + l16) * 64 + slot);
#pragma unroll
            for (int i = 0; i < 4; i++)
#pragma unroll
                for (int j = 0; j < 4; j++)
                    acc[i][j] = __builtin_amdgcn_mfma_f32_16x16x32_bf16(af[i], bf[j], acc[i][j], 0, 0, 0);
        }
    }
#undef STAGE_AB

    if (blockIdx.z == 2) {
#pragma unroll
        for (int i = 0; i < 4; i++) {
#pragma unroll
            for (int j = 0; j < 4; j++) {
                int m = bm + wm + i * 16 + quad * 4;
                int c = bn + wn + j * 16 + l16;
                int b = m >> 11, nn = m & 2047, h = c >> 6, dd = c & 63;
                short4v pk;
                pk.x = f2bs(acc[i][j][0]);
                pk.y = f2bs(acc[i][j][1]);
                pk.z = f2bs(acc[i][j][2]);
                pk.w = f2bs(acc[i][j][3]);
                *(short4v*)(vtout + ((size_t)(b * 16 + h) * 64 + dd) * 2048 + nn) = pk;
            }
        }
    } else {
        short* dst = (blockIdx.z == 0) ? qout : kout;
        float qs = (blockIdx.z == 0) ? 0.180336881f : 1.0f;  // 0.125*log2(e) folded into Q
#pragma unroll
        for (int i = 0; i < 4; i++) {
#pragma unroll
            for (int j = 0; j < 4; j++) {
#pragma unroll
                for (int r = 0; r < 4; r++) {
                    int m = bm + wm + i * 16 + quad * 4 + r;
                    int c = bn + wn + j * 16 + l16;
                    dst[((size_t)((m >> 11) * 16 + (c >> 6)) * 2048 + (m & 2047)) * 64 + (c & 63)] =
                        f2bs(acc[i][j][r] * qs);
                }
            }
        }
    }
}

// ---------------- Flash attention v2c: v2b minus sched_barrier pinning, plus T5 setprio ----------------
// Change vs v2b (m141 lesson: order-pinning defeats the scheduler): the 6 sched_barrier(0) per tile
// are replaced by plain `s_barrier` with a "memory" clobber — the clobber orders all LDS/VMEM ops
// (the only hazardous ops here); register-only MFMA consume their ds_read inputs before the next
// barrier, so rule-#18's hoist hole doesn't apply. setprio(1) wraps the QK and PV MFMA clusters.
__global__ __launch_bounds__(256, 2) void attn(const short* __restrict__ q,
                                               const short* __restrict__ k,
                                               const short* __restrict__ vt,
                                               float* __restrict__ out) {
    __shared__ short Ks[2][128 * 64];   // [key][d], 16B slot = chunk ^ (key&7)
    __shared__ short Vs[2][64 * 128];   // [d][key], 16B slot = (c&8)|((c^(d&7))&7)

    int tid = threadIdx.x;
    int lane = tid & 63;
    int wid = tid >> 6;
    int l32 = lane & 31;
    int half = lane >> 5;   // 0/1

    int flat = blockIdx.x;
    int xcd = flat & 7;
    int slot = flat >> 3;            // 0..63
    int bh = xcd * 8 + (slot >> 3);  // 8 (b,h) per XCD
    int qx = slot & 7;
    int b = bh >> 4, h = bh & 15;

    const short* qp = q + (size_t)(b * 16 + h) * 2048 * 64;
    const short* kp = k + (size_t)(b * 16 + h) * 2048 * 64;
    const short* vp = vt + (size_t)(b * 16 + h) * 64 * 2048;

    // K staging: 128x64. row = (tid>>3)+l*32, chunk = tid&7 (swizzled at source)
    int krow = tid >> 3;
    int ksw = ((tid & 7) ^ (krow & 7)) * 8;
    // V staging: 64x128. d = (tid>>4)+l*16, chunk16 = tid&15
    int vd = tid >> 4;
    int vc = tid & 15;
    int vsw = ((vc & 8) | ((vc ^ vd) & 7)) * 8;

#define BARRIER() asm volatile("s_barrier" ::: "memory")
#define STAGE_KV(cb, kvb) do { \
    _Pragma("unroll") for (int l = 0; l < 4; l++) { \
        const short* g = kp + (size_t)((kvb) + krow + l * 32) * 64 + ksw; \
        __builtin_amdgcn_global_load_lds((const GLOBAL_AS void*)g, \
            (LDS_AS void*)(&Ks[cb][0] + tid * 8 + l * 2048), 16, 0, 0); \
    } \
    _Pragma("unroll") for (int l = 0; l < 4; l++) { \
        const short* g = vp + (size_t)(vd + l * 16) * 2048 + (kvb) + vsw; \
        __builtin_amdgcn_global_load_lds((const GLOBAL_AS void*)g, \
            (LDS_AS void*)(&Vs[cb][0] + tid * 8 + l * 2048), 16, 0, 0); \
    } \
} while (0)

    for (int phase = 0; phase < 2; phase++) {
        int qt = (phase == 0) ? qx : (15 - qx);
        int qbase = qt * 128;
        int qrow_w = qbase + wid * 32;      // wave owns q-rows qrow_w .. qrow_w+31
        int qlane = qrow_w + l32;           // this lane's q-row (S^T col)

        // Q fragments as B-operand: n = l32 (q-row), k = half*8 + j, 4 K-steps over d=64
        short8 qf[4];
#pragma unroll
        for (int s = 0; s < 4; s++)
            qf[s] = *(const short8*)(qp + (size_t)qlane * 64 + s * 16 + half * 8);

        floatx16 oacc[2];
#pragma unroll
        for (int nt = 0; nt < 2; nt++)
#pragma unroll
            for (int e = 0; e < 16; e++) oacc[nt][e] = 0.f;
        float rs = 0.f;

        int ntiles = qt + 1;

        // phase prologue: guard vs previous phase's reads of buf0, then stage tile 0
        BARRIER();
        STAGE_KV(0, 0);

        for (int t = 0; t < ntiles; t++) {
            int cur = t & 1;
            int kvb = t * 128;

            // WAR guard: all waves done reading buf[cur^1] (tile t-1)
            BARRIER();
            if (t + 1 < ntiles) {
                STAGE_KV(cur ^ 1, kvb + 128);
                asm volatile("s_waitcnt vmcnt(8)" ::: "memory");  // tile-t loads (mine) done
            } else {
                asm volatile("s_waitcnt vmcnt(0)" ::: "memory");
            }
            BARRIER();   // RAW: tile-t LDS visible to all waves

            const short* Kc = &Ks[cur][0];
            const short* Vc = &Vs[cur][0];

            // ---- S^T[key 0..127][q 0..31] = K * Q^T ----
            floatx16 sacc[4];
#pragma unroll
            for (int kb = 0; kb < 4; kb++)
#pragma unroll
                for (int e = 0; e < 16; e++) sacc[kb][e] = 0.f;
            __builtin_amdgcn_s_setprio(1);
#pragma unroll
            for (int s = 0; s < 4; s++) {   // d-dim K-steps
#pragma unroll
                for (int kb = 0; kb < 4; kb++) {
                    int key = kb * 32 + l32;
                    int c = s * 2 + half;
                    short8 kf = *(const short8*)(Kc + key * 64 + ((c ^ (key & 7)) * 8));
                    sacc[kb] = __builtin_amdgcn_mfma_f32_32x32x16_bf16(kf, qf[s], sacc[kb], 0, 0, 0);
                }
            }
            __builtin_amdgcn_s_setprio(0);

            // ---- exp2 + mask (diag tile only) + local row-sum + in-register pack ----
            // quad g of block kb holds keys kb*32 + 8g + 4*half + {0..3} for q=l32:
            //   W0 = pk2(keys+0,+1), W1 = pk2(keys+2,+3)
            bool diag = (t == ntiles - 1) && (kvb + 127 > qrow_w);
            unsigned W0[4][4], W1[4][4];
#pragma unroll
            for (int kb = 0; kb < 4; kb++) {
#pragma unroll
                for (int e = 0; e < 16; e++) {
                    float p = __builtin_amdgcn_exp2f(sacc[kb][e]);
                    if (diag) {
                        int key = kvb + kb * 32 + (e & 3) + 8 * (e >> 2) + 4 * half;
                        p = (key > qlane) ? 0.f : p;
                    }
                    sacc[kb][e] = p;
                    rs += p;
                }
#pragma unroll
                for (int g = 0; g < 4; g++) {
                    W0[kb][g] = pk2(sacc[kb][4 * g + 0], sacc[kb][4 * g + 1]);
                    W1[kb][g] = pk2(sacc[kb][4 * g + 2], sacc[kb][4 * g + 3]);
                }
            }

            // ---- O += P * V : A-frag P[q=l32][keys 16s + 8*half + 0..7] via permlane32_swap ----
            // r0 = swap(W0[2sb], W0[2sb+1]): r0.x -> dword0 (keys +0,+1), r0.y -> dword2 (+4,+5)
            // r1 = swap(W1[2sb], W1[2sb+1]): r1.x -> dword1 (+2,+3),      r1.y -> dword3 (+6,+7)
            __builtin_amdgcn_s_setprio(1);
#pragma unroll
            for (int s = 0; s < 8; s++) {   // key K-steps of 16
                int kb = s >> 1;
                int g0 = (s & 1) * 2;       // quad for half-0 consumers
                int g1 = g0 + 1;            // quad for half-1 consumers
                iv2 r0 = __builtin_amdgcn_permlane32_swap(W0[kb][g0], W0[kb][g1], false, false);
                iv2 r1 = __builtin_amdgcn_permlane32_swap(W1[kb][g0], W1[kb][g1], false, false);
                union { int4 v; short8 s8; } pu;
                pu.v.x = r0.x; pu.v.y = r1.x; pu.v.z = r0.y; pu.v.w = r1.y;
                short8 pf = pu.s8;
#pragma unroll
                for (int nt = 0; nt < 2; nt++) {
                    int d = nt * 32 + l32;
                    int c = s * 2 + half;
                    int sl = (c & 8) | ((c ^ (d & 7)) & 7);
                    short8 vf = *(const short8*)(Vc + d * 128 + sl * 8);
                    oacc[nt] = __builtin_amdgcn_mfma_f32_32x32x16_bf16(pf, vf, oacc[nt], 0, 0, 0);
                }
            }
            __builtin_amdgcn_s_setprio(0);
        }

        // ---- epilogue: rows of O live across lanes; fetch 1/l via shuffle ----
        float tot = rs + __shfl_xor(rs, 32);
        float inv = 1.0f / tot;
        float invr[16];
#pragma unroll
        for (int e = 0; e < 16; e++)
            invr[e] = __shfl(inv, (e & 3) + 8 * (e >> 2) + 4 * half);
#pragma unroll
        for (int nt = 0; nt < 2; nt++) {
#pragma unroll
            for (int e = 0; e < 16; e++) {
                int r = (e & 3) + 8 * (e >> 2) + 4 * half;
                int nn = qrow_w + r;
                out[((size_t)b * 2048 + nn) * 1024 + h * 64 + nt * 32 + l32] = oacc[nt][e] * invr[e];
            }
        }
    }
#undef STAGE_KV
#undef BARRIER
}

extern "C" void kernel_launch(void* const* d_in, const int* in_sizes, int n_in,
                              void* d_out, int out_size, void* d_ws, size_t ws_size,
                              hipStream_t stream) {
    const float* x = (const float*)d_in[0];
    const float* Wq = (const float*)d_in[1];
    const float* Wk = (const float*)d_in[2];
    const float* Wv = (const float*)d_in[3];
    float* out = (float*)d_out;
    char* ws = (char*)d_ws;

    short* xb = (short*)ws;                          // 16 MB: [8192,1024] bf16
    short* wb = (short*)(ws + (16u << 20));          //  6 MB: [3,1024,1024] bf16
    short* qb = (short*)(ws + (22u << 20));          // 16 MB: [4,16,2048,64]
    short* kb = (short*)(ws + (38u << 20));          // 16 MB: [4,16,2048,64]
    short* vtb = (short*)(ws + (54u << 20));         // 16 MB: [4,16,64,2048]

    cast_all<<<8192 + 3 * 1024, 256, 0, stream>>>(x, Wq, Wk, Wv, xb, wb);
    qkv_gemm<<<dim3(64, 8, 3), 256, 0, stream>>>(xb, wb, qb, kb, vtb);
    attn<<<512, 256, 0, stream>>>(qb, kb, vtb, out);
}